// Round 1
// baseline (1468.536 us; speedup 1.0000x reference)
//
#include <hip/hip_runtime.h>
#include <hip/hip_bf16.h>
#include <math.h>

// ---------------------------------------------------------------------------
// CollaborativeExpertsWrapper: f32 correctness-first baseline.
// Pipeline:
//   om   = mean_t(o)                      (128,512)
//   oo   = normalize(om @ expand_W + b)   (128,1024)
//   per modality m in {rgb(K=2048), audio(K=128)}:
//     q/k/v = X @ W + b                   (8192,512) each   <-- dominant GEMMs
//     attn per (b,h): softmax(qk^T/sqrt(128)) @ v, mean over t -> pp (128,512)
//     pooled = pp @ Wo + bo; f = pooled @ W2 + b2 -> feat[:, m*512:+512]
//   s1[i,b] = oo[b]·feat[(b-i)%128]; s2[i,b] = feat[b]·oo[(b-i)%128]
//   final: margin-ranking loss + top-1 acc, 2 scalars.
// ---------------------------------------------------------------------------

// workspace offsets (floats)
enum : size_t {
  OFF_PARTIAL = 0,                          // 128*16*512
  OFF_OM      = OFF_PARTIAL + (size_t)128*16*512,
  OFF_OO      = OFF_OM + (size_t)128*512,
  OFF_Q       = OFF_OO + (size_t)128*1024,
  OFF_K       = OFF_Q + (size_t)8192*512,
  OFF_V       = OFF_K + (size_t)8192*512,
  OFF_PP      = OFF_V + (size_t)8192*512,
  OFF_PO      = OFF_PP + (size_t)128*512,
  OFF_FEAT    = OFF_PO + (size_t)128*512,
  OFF_S1      = OFF_FEAT + (size_t)128*1024,
  OFF_S2      = OFF_S1 + (size_t)128*128,
  OFF_END     = OFF_S2 + (size_t)128*128
};

// ---- o.mean(axis=1): stage 1 partial sums over 64-row chunks ---------------
__global__ __launch_bounds__(256) void mean_partial_k(const float* __restrict__ o,
                                                      float* __restrict__ part) {
  int c = blockIdx.x, b = blockIdx.y;            // chunk 0..15, batch 0..127
  const float* base = o + ((size_t)b * 1024 + (size_t)c * 64) * 512;
  int d2 = threadIdx.x * 2;
  float sx = 0.f, sy = 0.f;
  for (int t = 0; t < 64; ++t) {
    float2 v = *(const float2*)(base + (size_t)t * 512 + d2);
    sx += v.x; sy += v.y;
  }
  float* dst = part + ((size_t)b * 16 + c) * 512 + d2;
  dst[0] = sx; dst[1] = sy;
}

__global__ __launch_bounds__(512) void finalize_mean_k(const float* __restrict__ part,
                                                       float* __restrict__ om) {
  int b = blockIdx.x, d = threadIdx.x;
  float s = 0.f;
  for (int c = 0; c < 16; ++c) s += part[((size_t)b * 16 + c) * 512 + d];
  om[(size_t)b * 512 + d] = s * (1.f / 1024.f);
}

// ---- generic f32 GEMM: C[M,N] = A[M,K] @ W[K,N] + bias, 64x64 tile ---------
__global__ __launch_bounds__(256) void gemm_f32_k(
    const float* __restrict__ A, int lda,
    const float* __restrict__ W, int ldw,
    const float* __restrict__ bias,
    float* __restrict__ C, int ldc,
    int M, int N, int K) {
  __shared__ float As[16][65];   // [k][m], +1 pad
  __shared__ float Ws[16][64];   // [k][n]
  int tid = threadIdx.x;
  int tx = tid & 15, ty = tid >> 4;
  int row0 = blockIdx.y * 64;
  int col0 = blockIdx.x * 64;
  float acc[4][4] = {};
  int ar = tid >> 2;             // 0..63
  int ac = (tid & 3) << 2;       // 0,4,8,12
  int wr = tid >> 4;             // 0..15
  int wc = (tid & 15) << 2;      // 0..60
  for (int k0 = 0; k0 < K; k0 += 16) {
    float4 av = *(const float4*)(A + (size_t)(row0 + ar) * lda + k0 + ac);
    As[ac + 0][ar] = av.x; As[ac + 1][ar] = av.y;
    As[ac + 2][ar] = av.z; As[ac + 3][ar] = av.w;
    float4 wv = *(const float4*)(W + (size_t)(k0 + wr) * ldw + col0 + wc);
    *(float4*)&Ws[wr][wc] = wv;
    __syncthreads();
#pragma unroll
    for (int k = 0; k < 16; ++k) {
      float a0 = As[k][(ty << 2) + 0], a1 = As[k][(ty << 2) + 1];
      float a2 = As[k][(ty << 2) + 2], a3 = As[k][(ty << 2) + 3];
      float4 w = *(const float4*)&Ws[k][tx << 2];
      acc[0][0] += a0 * w.x; acc[0][1] += a0 * w.y; acc[0][2] += a0 * w.z; acc[0][3] += a0 * w.w;
      acc[1][0] += a1 * w.x; acc[1][1] += a1 * w.y; acc[1][2] += a1 * w.z; acc[1][3] += a1 * w.w;
      acc[2][0] += a2 * w.x; acc[2][1] += a2 * w.y; acc[2][2] += a2 * w.z; acc[2][3] += a2 * w.w;
      acc[3][0] += a3 * w.x; acc[3][1] += a3 * w.y; acc[3][2] += a3 * w.z; acc[3][3] += a3 * w.w;
    }
    __syncthreads();
  }
  float4 bv = *(const float4*)(bias + col0 + (tx << 2));
#pragma unroll
  for (int i = 0; i < 4; ++i) {
    float4 ov;
    ov.x = acc[i][0] + bv.x; ov.y = acc[i][1] + bv.y;
    ov.z = acc[i][2] + bv.z; ov.w = acc[i][3] + bv.w;
    *(float4*)(C + (size_t)(row0 + (ty << 2) + i) * ldc + col0 + (tx << 2)) = ov;
  }
}

// ---- attention pool per (b,h): softmax(q k^T / sqrt(128)) @ v, mean_t ------
__global__ __launch_bounds__(256) void attn_pool_k(
    const float* __restrict__ q, const float* __restrict__ k,
    const float* __restrict__ v, float* __restrict__ pooled) {
  __shared__ float qs[64][128];   // 32 KB
  __shared__ float ks[16][129];   // 8.06 KB (pad kills 16-way conflict)
  __shared__ float sc[64][65];    // 16.25 KB
  int h = blockIdx.x, b = blockIdx.y;
  int tid = threadIdx.x;
  size_t rowbase = (size_t)b * 64;
  for (int i = tid; i < 64 * 128; i += 256) {
    int t = i >> 7, d = i & 127;
    qs[t][d] = q[(rowbase + t) * 512 + h * 128 + d];
  }
  __syncthreads();
  const float scale = 0.08838834764831845f;  // 1/sqrt(128)
  int sl = tid & 15, tg = tid >> 4;
  for (int chunk = 0; chunk < 4; ++chunk) {
    for (int i = tid; i < 16 * 128; i += 256) {
      int r = i >> 7, d = i & 127;
      ks[r][d] = k[(rowbase + chunk * 16 + r) * 512 + h * 128 + d];
    }
    __syncthreads();
#pragma unroll
    for (int rep = 0; rep < 4; ++rep) {
      int t = tg * 4 + rep;
      float a = 0.f;
      for (int d = 0; d < 128; ++d) a += qs[t][d] * ks[sl][d];
      sc[t][chunk * 16 + sl] = a * scale;
    }
    __syncthreads();
  }
  {  // softmax over s per row t: 4 lanes per row
    int r = tid >> 2, quad = tid & 3;
    float mx = -INFINITY;
    for (int j = quad; j < 64; j += 4) mx = fmaxf(mx, sc[r][j]);
    mx = fmaxf(mx, __shfl_xor(mx, 1));
    mx = fmaxf(mx, __shfl_xor(mx, 2));
    float sum = 0.f;
    for (int j = quad; j < 64; j += 4) { float e = expf(sc[r][j] - mx); sc[r][j] = e; sum += e; }
    sum += __shfl_xor(sum, 1);
    sum += __shfl_xor(sum, 2);
    float inv = 1.f / sum;
    for (int j = quad; j < 64; j += 4) sc[r][j] *= inv;
  }
  __syncthreads();
  {  // out = a @ v, accumulate mean over t
    int dd = tid & 127, t2 = tid >> 7;
    float psum = 0.f;
    for (int t = t2; t < 64; t += 2) {
      float a = 0.f;
      for (int s = 0; s < 64; ++s) a += sc[t][s] * v[(rowbase + s) * 512 + h * 128 + dd];
      psum += a;
    }
    // two contributions per address (t2=0,1): f32 add is commutative -> deterministic
    atomicAdd(&pooled[(size_t)b * 512 + h * 128 + dd], psum * (1.f / 64.f));
  }
}

// ---- row L2 normalize ------------------------------------------------------
__global__ __launch_bounds__(256) void l2norm_k(float* __restrict__ x, int C) {
  int b = blockIdx.x;
  float* row = x + (size_t)b * C;
  int tid = threadIdx.x;
  float ss = 0.f;
  for (int c = tid; c < C; c += 256) { float v = row[c]; ss += v * v; }
#pragma unroll
  for (int off = 32; off >= 1; off >>= 1) ss += __shfl_down(ss, off);
  __shared__ float wsum[4];
  if ((tid & 63) == 0) wsum[tid >> 6] = ss;
  __syncthreads();
  float total = wsum[0] + wsum[1] + wsum[2] + wsum[3];
  float inv = 1.f / fmaxf(sqrtf(total), 1e-12f);
  for (int c = tid; c < C; c += 256) row[c] *= inv;
}

// ---- ranking score matrices ------------------------------------------------
__global__ __launch_bounds__(256) void rank_scores_k(const float* __restrict__ oo,
                                                     const float* __restrict__ feat,
                                                     float* __restrict__ s1,
                                                     float* __restrict__ s2) {
  int b = blockIdx.x, i = blockIdx.y;
  int j = (b - i + 128) & 127;
  const float* a1 = oo + (size_t)b * 1024;
  const float* b1 = feat + (size_t)j * 1024;
  const float* a2 = feat + (size_t)b * 1024;
  const float* b2 = oo + (size_t)j * 1024;
  int tid = threadIdx.x;
  float p1 = 0.f, p2 = 0.f;
  for (int c = tid; c < 1024; c += 256) { p1 += a1[c] * b1[c]; p2 += a2[c] * b2[c]; }
#pragma unroll
  for (int off = 32; off >= 1; off >>= 1) { p1 += __shfl_down(p1, off); p2 += __shfl_down(p2, off); }
  __shared__ float r1[4], r2[4];
  if ((tid & 63) == 0) { r1[tid >> 6] = p1; r2[tid >> 6] = p2; }
  __syncthreads();
  if (tid == 0) {
    s1[i * 128 + b] = r1[0] + r1[1] + r1[2] + r1[3];
    s2[i * 128 + b] = r2[0] + r2[1] + r2[2] + r2[3];
  }
}

// ---- final loss/acc --------------------------------------------------------
__global__ __launch_bounds__(128) void final_k(const float* __restrict__ s1,
                                               const float* __restrict__ s2,
                                               const int* __restrict__ gmask,
                                               float* __restrict__ out) {
  __shared__ float cm[2][128], vd[2][128], tp[2][128], cv[2][128];
  __shared__ int gm[128];
  int b = threadIdx.x;
  gm[b] = gmask[b];
  __syncthreads();
  for (int r = 0; r < 2; ++r) {
    const float* S = (r == 0) ? s1 : s2;
    bool gb = gm[b] != 0;
    float s0 = S[b];
    int cnt = 0;
    float lsum = 0.f, selsum = 0.f, smax = -INFINITY;
    bool anym = false;
    for (int i = 0; i < 128; ++i) {
      int j = (b - i + 128) & 127;
      bool m = gb && (gm[j] != 0);
      float sv = S[i * 128 + b];
      if (m) {
        selsum += sv; anym = true;
        smax = fmaxf(smax, sv);
        if (i >= 1) { cnt++; lsum += fmaxf(0.f, 1.f + sv - s0); }
      }
    }
    cm[r][b] = (cnt > 0) ? (lsum / (float)cnt) : 0.f;
    vd[r][b] = (cnt > 0) ? 1.f : 0.f;
    bool colvalid = (selsum != 0.f) && anym;
    tp[r][b] = (colvalid && (s0 >= smax)) ? 1.f : 0.f;
    cv[r][b] = colvalid ? 1.f : 0.f;
  }
  __syncthreads();
  if (b == 0) {
    float loss = 0.f, acc = 0.f;
    for (int r = 0; r < 2; ++r) {
      float scm = 0, svd = 0, stp = 0, scv = 0;
      for (int i = 0; i < 128; ++i) { scm += cm[r][i]; svd += vd[r][i]; stp += tp[r][i]; scv += cv[r][i]; }
      loss += scm / fmaxf(svd, 1.f);
      acc += stp / fmaxf(scv, 1.f);
    }
    out[0] = loss;
    out[1] = acc * 0.5f;
  }
}

extern "C" void kernel_launch(void* const* d_in, const int* in_sizes, int n_in,
                              void* d_out, int out_size, void* d_ws, size_t ws_size,
                              hipStream_t stream) {
  const float* o     = (const float*)d_in[0];
  const float* rgb   = (const float*)d_in[1];
  const float* audio = (const float*)d_in[2];
  const int* gmask   = (const int*)d_in[3];
  const float* W[2][10];
  for (int m = 0; m < 2; ++m)
    for (int w = 0; w < 10; ++w) W[m][w] = (const float*)d_in[4 + m * 10 + w];
  const float* expand_W = (const float*)d_in[24];
  const float* expand_b = (const float*)d_in[25];

  float* ws = (float*)d_ws;
  float* part = ws + OFF_PARTIAL;
  float* om   = ws + OFF_OM;
  float* oo   = ws + OFF_OO;
  float* qb   = ws + OFF_Q;
  float* kb   = ws + OFF_K;
  float* vb   = ws + OFF_V;
  float* pp   = ws + OFF_PP;
  float* po   = ws + OFF_PO;
  float* feat = ws + OFF_FEAT;
  float* s1   = ws + OFF_S1;
  float* s2   = ws + OFF_S2;

  // oo branch
  mean_partial_k<<<dim3(16, 128), 256, 0, stream>>>(o, part);
  finalize_mean_k<<<128, 512, 0, stream>>>(part, om);
  gemm_f32_k<<<dim3(16, 2), 256, 0, stream>>>(om, 512, expand_W, 1024, expand_b,
                                              oo, 1024, 128, 1024, 512);
  l2norm_k<<<128, 256, 0, stream>>>(oo, 1024);

  // modality branches
  const float* Xs[2] = {rgb, audio};
  const int Ks[2] = {2048, 128};
  for (int m = 0; m < 2; ++m) {
    const float* X = Xs[m];
    int K = Ks[m];
    gemm_f32_k<<<dim3(8, 128), 256, 0, stream>>>(X, K, W[m][0], 512, W[m][1], qb, 512, 8192, 512, K);
    gemm_f32_k<<<dim3(8, 128), 256, 0, stream>>>(X, K, W[m][2], 512, W[m][3], kb, 512, 8192, 512, K);
    gemm_f32_k<<<dim3(8, 128), 256, 0, stream>>>(X, K, W[m][4], 512, W[m][5], vb, 512, 8192, 512, K);
    hipMemsetAsync(pp, 0, 128 * 512 * sizeof(float), stream);
    attn_pool_k<<<dim3(4, 128), 256, 0, stream>>>(qb, kb, vb, pp);
    gemm_f32_k<<<dim3(8, 2), 256, 0, stream>>>(pp, 512, W[m][6], 512, W[m][7], po, 512, 128, 512, 512);
    gemm_f32_k<<<dim3(8, 2), 256, 0, stream>>>(po, 512, W[m][8], 512, W[m][9],
                                               feat + m * 512, 1024, 128, 512, 512);
  }

  // ranking
  rank_scores_k<<<dim3(128, 128), 256, 0, stream>>>(oo, feat, s1, s2);
  final_k<<<1, 128, 0, stream>>>(s1, s2, gmask, (float*)d_out);
}

// Round 2
// 645.415 us; speedup vs baseline: 2.2753x; 2.2753x over previous
//
#include <hip/hip_runtime.h>
#include <hip/hip_bf16.h>
#include <math.h>

// ---------------------------------------------------------------------------
// CollaborativeExpertsWrapper — round 2: bf16 MFMA q/k/v projections.
//   om   = mean_t(o); oo = normalize(om @ expand_W + b)          [f32]
//   per modality: q/k/v = X @ W + b  -> bf16 MFMA (f32 accum, f32 out)
//     attn pool (f32), Wo/W2 small GEMMs (f32)
//   ranking -> 2 scalars.
// ---------------------------------------------------------------------------

using bf16x8 = __attribute__((ext_vector_type(8))) __bf16;
using f32x4  = __attribute__((ext_vector_type(4))) float;

// ---- workspace byte offsets ------------------------------------------------
enum : size_t {
  B_PART = 0,                                   // 128*16*512 f32 = 4 MB
  B_OM   = B_PART + (size_t)128*16*512*4,
  B_OO   = B_OM   + (size_t)128*512*4,
  B_Q    = B_OO   + (size_t)128*1024*4,
  B_K    = B_Q    + (size_t)8192*512*4,
  B_V    = B_K    + (size_t)8192*512*4,
  B_PP   = B_V    + (size_t)8192*512*4,
  B_PO   = B_PP   + (size_t)128*512*4,
  B_FEAT = B_PO   + (size_t)128*512*4,
  B_S1   = B_FEAT + (size_t)128*1024*4,
  B_S2   = B_S1   + (size_t)128*128*4,
  B_XBF  = B_S2   + (size_t)128*128*4,          // 8192*2048 bf16 = 32 MB (reused)
  B_WT   = B_XBF  + (size_t)8192*2048*2,        // 3 x 512*2048 bf16 = 6 MB (reused)
  B_END  = B_WT   + (size_t)3*512*2048*2
};

// ---- o.mean(axis=1) --------------------------------------------------------
__global__ __launch_bounds__(256) void mean_partial_k(const float* __restrict__ o,
                                                      float* __restrict__ part) {
  int c = blockIdx.x, b = blockIdx.y;
  const float* base = o + ((size_t)b * 1024 + (size_t)c * 64) * 512;
  int d2 = threadIdx.x * 2;
  float sx = 0.f, sy = 0.f;
  for (int t = 0; t < 64; ++t) {
    float2 v = *(const float2*)(base + (size_t)t * 512 + d2);
    sx += v.x; sy += v.y;
  }
  float* dst = part + ((size_t)b * 16 + c) * 512 + d2;
  dst[0] = sx; dst[1] = sy;
}

__global__ __launch_bounds__(512) void finalize_mean_k(const float* __restrict__ part,
                                                       float* __restrict__ om) {
  int b = blockIdx.x, d = threadIdx.x;
  float s = 0.f;
  for (int c = 0; c < 16; ++c) s += part[((size_t)b * 16 + c) * 512 + d];
  om[(size_t)b * 512 + d] = s * (1.f / 1024.f);
}

// ---- f32 GEMM (small matrices only) ---------------------------------------
__global__ __launch_bounds__(256) void gemm_f32_k(
    const float* __restrict__ A, int lda,
    const float* __restrict__ W, int ldw,
    const float* __restrict__ bias,
    float* __restrict__ C, int ldc,
    int M, int N, int K) {
  __shared__ float As[16][65];
  __shared__ float Ws[16][64];
  int tid = threadIdx.x;
  int tx = tid & 15, ty = tid >> 4;
  int row0 = blockIdx.y * 64;
  int col0 = blockIdx.x * 64;
  float acc[4][4] = {};
  int ar = tid >> 2;
  int ac = (tid & 3) << 2;
  int wr = tid >> 4;
  int wc = (tid & 15) << 2;
  for (int k0 = 0; k0 < K; k0 += 16) {
    float4 av = *(const float4*)(A + (size_t)(row0 + ar) * lda + k0 + ac);
    As[ac + 0][ar] = av.x; As[ac + 1][ar] = av.y;
    As[ac + 2][ar] = av.z; As[ac + 3][ar] = av.w;
    float4 wv = *(const float4*)(W + (size_t)(k0 + wr) * ldw + col0 + wc);
    *(float4*)&Ws[wr][wc] = wv;
    __syncthreads();
#pragma unroll
    for (int k = 0; k < 16; ++k) {
      float a0 = As[k][(ty << 2) + 0], a1 = As[k][(ty << 2) + 1];
      float a2 = As[k][(ty << 2) + 2], a3 = As[k][(ty << 2) + 3];
      float4 w = *(const float4*)&Ws[k][tx << 2];
      acc[0][0] += a0 * w.x; acc[0][1] += a0 * w.y; acc[0][2] += a0 * w.z; acc[0][3] += a0 * w.w;
      acc[1][0] += a1 * w.x; acc[1][1] += a1 * w.y; acc[1][2] += a1 * w.z; acc[1][3] += a1 * w.w;
      acc[2][0] += a2 * w.x; acc[2][1] += a2 * w.y; acc[2][2] += a2 * w.z; acc[2][3] += a2 * w.w;
      acc[3][0] += a3 * w.x; acc[3][1] += a3 * w.y; acc[3][2] += a3 * w.z; acc[3][3] += a3 * w.w;
    }
    __syncthreads();
  }
  float4 bv = *(const float4*)(bias + col0 + (tx << 2));
#pragma unroll
  for (int i = 0; i < 4; ++i) {
    float4 ov;
    ov.x = acc[i][0] + bv.x; ov.y = acc[i][1] + bv.y;
    ov.z = acc[i][2] + bv.z; ov.w = acc[i][3] + bv.w;
    *(float4*)(C + (size_t)(row0 + (ty << 2) + i) * ldc + col0 + (tx << 2)) = ov;
  }
}

// ---- casts -----------------------------------------------------------------
__device__ __forceinline__ unsigned short f2bf(float f) {
  __hip_bfloat16 h = __float2bfloat16(f);
  return __builtin_bit_cast(unsigned short, h);
}

__global__ __launch_bounds__(256) void cast_k(const float* __restrict__ x,
                                              unsigned short* __restrict__ y, int n) {
  int i = (blockIdx.x * 256 + threadIdx.x) * 4;
  int stride = gridDim.x * 1024;
  for (; i < n; i += stride) {
    float4 v = *(const float4*)(x + i);
    ushort4 u;
    u.x = f2bf(v.x); u.y = f2bf(v.y); u.z = f2bf(v.z); u.w = f2bf(v.w);
    *(ushort4*)(y + i) = u;
  }
}

// W[K][N] f32 -> Wt[N][K] bf16
__global__ void castT_k(const float* __restrict__ W, unsigned short* __restrict__ Wt,
                        int K, int N) {
  __shared__ float t[32][33];
  int n0 = blockIdx.x * 32, k0 = blockIdx.y * 32;
  int tx = threadIdx.x, ty = threadIdx.y;  // (32, 8)
#pragma unroll
  for (int i = 0; i < 4; ++i)
    t[ty + 8 * i][tx] = W[(size_t)(k0 + ty + 8 * i) * N + n0 + tx];
  __syncthreads();
#pragma unroll
  for (int i = 0; i < 4; ++i)
    Wt[(size_t)(n0 + ty + 8 * i) * K + k0 + tx] = f2bf(t[tx][ty + 8 * i]);
}

// ---- bf16 MFMA GEMM: C = A[M,K] @ Wt[N,K]^T + bias; q/k/v fused via z ------
struct QkvArgs {
  const unsigned short* Wt[3];
  const float* bias[3];
  float* out[3];
};

__device__ __forceinline__ void stage16(const void* g, void* l) {
  __builtin_amdgcn_global_load_lds((const __attribute__((address_space(1))) void*)g,
                                   (__attribute__((address_space(3))) void*)l, 16, 0, 0);
}

__global__ __launch_bounds__(256) void gemm_bf16_qkv(
    const unsigned short* __restrict__ A,  // bf16 [M][K]
    QkvArgs args, int K, int ldc) {
  __shared__ unsigned short As[128 * 32];  // [row][k] 64B rows
  __shared__ unsigned short Bs[128 * 32];  // [col][k]
  const unsigned short* Bt = args.Wt[blockIdx.z];
  const float* bias = args.bias[blockIdx.z];
  float* C = args.out[blockIdx.z];

  int tid = threadIdx.x;
  int l = tid & 63, w = tid >> 6;
  int row0 = blockIdx.y * 128, col0 = blockIdx.x * 128;
  int wrow = (w & 1) * 64, wcol = (w >> 1) * 64;
  int kg = l >> 4, lr = l & 15;

  f32x4 acc[4][4] = {};

  for (int k0 = 0; k0 < K; k0 += 32) {
    // stage A,B tiles (128x32 bf16 each): 2 insts per wave per tile
#pragma unroll
    for (int i = 0; i < 2; ++i) {
      int c = w * 128 + i * 64 + l;      // chunk id (16B)
      int r = c >> 2, s = (c & 3) * 8;   // row, k-offset (elems)
      stage16(A + (size_t)(row0 + r) * K + k0 + s, (char*)As + (size_t)(w * 128 + i * 64) * 16);
      stage16(Bt + (size_t)(col0 + r) * K + k0 + s, (char*)Bs + (size_t)(w * 128 + i * 64) * 16);
    }
    __syncthreads();
    bf16x8 af[4], bfr[4];
#pragma unroll
    for (int m = 0; m < 4; ++m) {
      af[m]  = *(const bf16x8*)(As + (size_t)(wrow + m * 16 + lr) * 32 + kg * 8);
      bfr[m] = *(const bf16x8*)(Bs + (size_t)(wcol + m * 16 + lr) * 32 + kg * 8);
    }
#pragma unroll
    for (int m = 0; m < 4; ++m)
#pragma unroll
      for (int n = 0; n < 4; ++n)
        acc[m][n] = __builtin_amdgcn_mfma_f32_16x16x32_bf16(af[m], bfr[n], acc[m][n], 0, 0, 0);
    __syncthreads();
  }

  int orow = row0 + wrow + kg * 4;
  int ocol = col0 + wcol + lr;
  float bv[4];
#pragma unroll
  for (int n = 0; n < 4; ++n) bv[n] = bias[ocol + n * 16];
#pragma unroll
  for (int m = 0; m < 4; ++m)
#pragma unroll
    for (int n = 0; n < 4; ++n)
#pragma unroll
      for (int j = 0; j < 4; ++j)
        C[(size_t)(orow + m * 16 + j) * ldc + ocol + n * 16] = acc[m][n][j] + bv[n];
}

// ---- attention pool per (b,h) ----------------------------------------------
__global__ __launch_bounds__(256) void attn_pool_k(
    const float* __restrict__ q, const float* __restrict__ k,
    const float* __restrict__ v, float* __restrict__ pooled) {
  __shared__ float qs[64][128];
  __shared__ float ks[16][129];
  __shared__ float sc[64][65];
  int h = blockIdx.x, b = blockIdx.y;
  int tid = threadIdx.x;
  size_t rowbase = (size_t)b * 64;
  for (int i = tid; i < 64 * 128; i += 256) {
    int t = i >> 7, d = i & 127;
    qs[t][d] = q[(rowbase + t) * 512 + h * 128 + d];
  }
  __syncthreads();
  const float scale = 0.08838834764831845f;
  int sl = tid & 15, tg = tid >> 4;
  for (int chunk = 0; chunk < 4; ++chunk) {
    for (int i = tid; i < 16 * 128; i += 256) {
      int r = i >> 7, d = i & 127;
      ks[r][d] = k[(rowbase + chunk * 16 + r) * 512 + h * 128 + d];
    }
    __syncthreads();
#pragma unroll
    for (int rep = 0; rep < 4; ++rep) {
      int t = tg * 4 + rep;
      float a = 0.f;
      for (int d = 0; d < 128; ++d) a += qs[t][d] * ks[sl][d];
      sc[t][chunk * 16 + sl] = a * scale;
    }
    __syncthreads();
  }
  {
    int r = tid >> 2, quad = tid & 3;
    float mx = -INFINITY;
    for (int j = quad; j < 64; j += 4) mx = fmaxf(mx, sc[r][j]);
    mx = fmaxf(mx, __shfl_xor(mx, 1));
    mx = fmaxf(mx, __shfl_xor(mx, 2));
    float sum = 0.f;
    for (int j = quad; j < 64; j += 4) { float e = expf(sc[r][j] - mx); sc[r][j] = e; sum += e; }
    sum += __shfl_xor(sum, 1);
    sum += __shfl_xor(sum, 2);
    float inv = 1.f / sum;
    for (int j = quad; j < 64; j += 4) sc[r][j] *= inv;
  }
  __syncthreads();
  {
    int dd = tid & 127, t2 = tid >> 7;
    float psum = 0.f;
    for (int t = t2; t < 64; t += 2) {
      float a = 0.f;
      for (int s = 0; s < 64; ++s) a += sc[t][s] * v[(rowbase + s) * 512 + h * 128 + dd];
      psum += a;
    }
    atomicAdd(&pooled[(size_t)b * 512 + h * 128 + dd], psum * (1.f / 64.f));
  }
}

// ---- row L2 normalize ------------------------------------------------------
__global__ __launch_bounds__(256) void l2norm_k(float* __restrict__ x, int C) {
  int b = blockIdx.x;
  float* row = x + (size_t)b * C;
  int tid = threadIdx.x;
  float ss = 0.f;
  for (int c = tid; c < C; c += 256) { float v = row[c]; ss += v * v; }
#pragma unroll
  for (int off = 32; off >= 1; off >>= 1) ss += __shfl_down(ss, off);
  __shared__ float wsum[4];
  if ((tid & 63) == 0) wsum[tid >> 6] = ss;
  __syncthreads();
  float total = wsum[0] + wsum[1] + wsum[2] + wsum[3];
  float inv = 1.f / fmaxf(sqrtf(total), 1e-12f);
  for (int c = tid; c < C; c += 256) row[c] *= inv;
}

// ---- ranking score matrices ------------------------------------------------
__global__ __launch_bounds__(256) void rank_scores_k(const float* __restrict__ oo,
                                                     const float* __restrict__ feat,
                                                     float* __restrict__ s1,
                                                     float* __restrict__ s2) {
  int b = blockIdx.x, i = blockIdx.y;
  int j = (b - i + 128) & 127;
  const float* a1 = oo + (size_t)b * 1024;
  const float* b1 = feat + (size_t)j * 1024;
  const float* a2 = feat + (size_t)b * 1024;
  const float* b2 = oo + (size_t)j * 1024;
  int tid = threadIdx.x;
  float p1 = 0.f, p2 = 0.f;
  for (int c = tid; c < 1024; c += 256) { p1 += a1[c] * b1[c]; p2 += a2[c] * b2[c]; }
#pragma unroll
  for (int off = 32; off >= 1; off >>= 1) { p1 += __shfl_down(p1, off); p2 += __shfl_down(p2, off); }
  __shared__ float r1[4], r2[4];
  if ((tid & 63) == 0) { r1[tid >> 6] = p1; r2[tid >> 6] = p2; }
  __syncthreads();
  if (tid == 0) {
    s1[i * 128 + b] = r1[0] + r1[1] + r1[2] + r1[3];
    s2[i * 128 + b] = r2[0] + r2[1] + r2[2] + r2[3];
  }
}

// ---- final loss/acc --------------------------------------------------------
__global__ __launch_bounds__(128) void final_k(const float* __restrict__ s1,
                                               const float* __restrict__ s2,
                                               const int* __restrict__ gmask,
                                               float* __restrict__ out) {
  __shared__ float cm[2][128], vd[2][128], tp[2][128], cv[2][128];
  __shared__ int gm[128];
  int b = threadIdx.x;
  gm[b] = gmask[b];
  __syncthreads();
  for (int r = 0; r < 2; ++r) {
    const float* S = (r == 0) ? s1 : s2;
    bool gb = gm[b] != 0;
    float s0 = S[b];
    int cnt = 0;
    float lsum = 0.f, selsum = 0.f, smax = -INFINITY;
    bool anym = false;
    for (int i = 0; i < 128; ++i) {
      int j = (b - i + 128) & 127;
      bool m = gb && (gm[j] != 0);
      float sv = S[i * 128 + b];
      if (m) {
        selsum += sv; anym = true;
        smax = fmaxf(smax, sv);
        if (i >= 1) { cnt++; lsum += fmaxf(0.f, 1.f + sv - s0); }
      }
    }
    cm[r][b] = (cnt > 0) ? (lsum / (float)cnt) : 0.f;
    vd[r][b] = (cnt > 0) ? 1.f : 0.f;
    bool colvalid = (selsum != 0.f) && anym;
    tp[r][b] = (colvalid && (s0 >= smax)) ? 1.f : 0.f;
    cv[r][b] = colvalid ? 1.f : 0.f;
  }
  __syncthreads();
  if (b == 0) {
    float loss = 0.f, acc = 0.f;
    for (int r = 0; r < 2; ++r) {
      float scm = 0, svd = 0, stp = 0, scv = 0;
      for (int i = 0; i < 128; ++i) { scm += cm[r][i]; svd += vd[r][i]; stp += tp[r][i]; scv += cv[r][i]; }
      loss += scm / fmaxf(svd, 1.f);
      acc += stp / fmaxf(scv, 1.f);
    }
    out[0] = loss;
    out[1] = acc * 0.5f;
  }
}

extern "C" void kernel_launch(void* const* d_in, const int* in_sizes, int n_in,
                              void* d_out, int out_size, void* d_ws, size_t ws_size,
                              hipStream_t stream) {
  const float* o     = (const float*)d_in[0];
  const float* rgb   = (const float*)d_in[1];
  const float* audio = (const float*)d_in[2];
  const int* gmask   = (const int*)d_in[3];
  const float* W[2][10];
  for (int m = 0; m < 2; ++m)
    for (int w = 0; w < 10; ++w) W[m][w] = (const float*)d_in[4 + m * 10 + w];
  const float* expand_W = (const float*)d_in[24];
  const float* expand_b = (const float*)d_in[25];

  char* ws = (char*)d_ws;
  float* part = (float*)(ws + B_PART);
  float* om   = (float*)(ws + B_OM);
  float* oo   = (float*)(ws + B_OO);
  float* qb   = (float*)(ws + B_Q);
  float* kb   = (float*)(ws + B_K);
  float* vb   = (float*)(ws + B_V);
  float* pp   = (float*)(ws + B_PP);
  float* po   = (float*)(ws + B_PO);
  float* feat = (float*)(ws + B_FEAT);
  float* s1   = (float*)(ws + B_S1);
  float* s2   = (float*)(ws + B_S2);
  unsigned short* xbf = (unsigned short*)(ws + B_XBF);
  unsigned short* wt0 = (unsigned short*)(ws + B_WT);
  unsigned short* wt1 = wt0 + (size_t)512 * 2048;
  unsigned short* wt2 = wt1 + (size_t)512 * 2048;

  // oo branch (f32)
  mean_partial_k<<<dim3(16, 128), 256, 0, stream>>>(o, part);
  finalize_mean_k<<<128, 512, 0, stream>>>(part, om);
  gemm_f32_k<<<dim3(16, 2), 256, 0, stream>>>(om, 512, expand_W, 1024, expand_b,
                                              oo, 1024, 128, 1024, 512);
  l2norm_k<<<128, 256, 0, stream>>>(oo, 1024);

  // modality branches
  const float* Xs[2] = {rgb, audio};
  const int Ks[2] = {2048, 128};
  for (int m = 0; m < 2; ++m) {
    const float* X = Xs[m];
    int K = Ks[m];
    int nelem = 8192 * K;
    cast_k<<<dim3(m == 0 ? 2048 : 512), 256, 0, stream>>>(X, xbf, nelem);
    castT_k<<<dim3(16, K / 32), dim3(32, 8), 0, stream>>>(W[m][0], wt0, K, 512);
    castT_k<<<dim3(16, K / 32), dim3(32, 8), 0, stream>>>(W[m][2], wt1, K, 512);
    castT_k<<<dim3(16, K / 32), dim3(32, 8), 0, stream>>>(W[m][4], wt2, K, 512);
    QkvArgs args;
    args.Wt[0] = wt0; args.Wt[1] = wt1; args.Wt[2] = wt2;
    args.bias[0] = W[m][1]; args.bias[1] = W[m][3]; args.bias[2] = W[m][5];
    args.out[0] = qb; args.out[1] = kb; args.out[2] = vb;
    gemm_bf16_qkv<<<dim3(4, 64, 3), 256, 0, stream>>>(xbf, args, K, 512);

    hipMemsetAsync(pp, 0, 128 * 512 * sizeof(float), stream);
    attn_pool_k<<<dim3(4, 128), 256, 0, stream>>>(qb, kb, vb, pp);
    gemm_f32_k<<<dim3(8, 2), 256, 0, stream>>>(pp, 512, W[m][6], 512, W[m][7], po, 512, 128, 512, 512);
    gemm_f32_k<<<dim3(8, 2), 256, 0, stream>>>(po, 512, W[m][8], 512, W[m][9],
                                               feat + m * 512, 1024, 128, 512, 512);
  }

  // ranking
  rank_scores_k<<<dim3(128, 128), 256, 0, stream>>>(oo, feat, s1, s2);
  final_k<<<1, 128, 0, stream>>>(s1, s2, gmask, (float*)d_out);
}

// Round 3
// 411.516 us; speedup vs baseline: 3.5686x; 1.5684x over previous
//
#include <hip/hip_runtime.h>
#include <hip/hip_bf16.h>
#include <math.h>

// ---------------------------------------------------------------------------
// CollaborativeExpertsWrapper — round 3.
//   oo  = normalize(mean_t(o) @ expand_W + b)                     [f32]
//   per modality: q,k (bf16) / v (f32) = X @ W + b  (bf16 MFMA, XCD swizzle)
//   attn pool via MFMA QK^T + t-mean-commuted vector*V             (fused z=2)
//   po/feat GEMMs batched over modalities (M=256)
//   ranking: G = oo @ feat^T (one 128x128 NT GEMM) + remap in final_k
// ---------------------------------------------------------------------------

using bf16x8 = __attribute__((ext_vector_type(8))) __bf16;
using f32x4  = __attribute__((ext_vector_type(4))) float;

// ---- workspace byte offsets ------------------------------------------------
enum : size_t {
  B_PART = 0,                                    // 128*32*512 f32 = 8 MB
  B_OM   = B_PART + (size_t)128*32*512*4,
  B_OO   = B_OM   + (size_t)128*512*4,
  B_G    = B_OO   + (size_t)128*1024*4,          // 128*128 f32
  B_PP   = B_G    + (size_t)128*128*4,           // [2][128][512] f32
  B_PO   = B_PP   + (size_t)2*128*512*4,
  B_FEAT = B_PO   + (size_t)2*128*512*4,         // [2][128][512] f32 (modality-major)
  B_QBF  = B_FEAT + (size_t)2*128*512*4,         // [2][8192][512] bf16 = 16 MB
  B_KBF  = B_QBF  + (size_t)2*8192*512*2,
  B_VF   = B_KBF  + (size_t)2*8192*512*2,        // [2][8192][512] f32 = 32 MB
  B_XBF  = B_VF   + (size_t)2*8192*512*4,        // 8192*2048 bf16 = 32 MB (reused)
  B_WT   = B_XBF  + (size_t)8192*2048*2,         // 3 x 512*2048 bf16 (reused)
  B_END  = B_WT   + (size_t)3*512*2048*2
};

// ---- o.mean(axis=1) --------------------------------------------------------
__global__ __launch_bounds__(256) void mean_partial_k(const float* __restrict__ o,
                                                      float* __restrict__ part) {
  int c = blockIdx.x, b = blockIdx.y;            // chunk 0..15, batch
  const float* base = o + ((size_t)b * 1024 + (size_t)c * 64) * 512;
  int d4 = (threadIdx.x & 127) << 2;
  int half = threadIdx.x >> 7;
  float4 s = {0.f, 0.f, 0.f, 0.f};
  for (int t = half; t < 64; t += 2) {
    float4 v = *(const float4*)(base + (size_t)t * 512 + d4);
    s.x += v.x; s.y += v.y; s.z += v.z; s.w += v.w;
  }
  *(float4*)(part + (((size_t)b * 16 + c) * 2 + half) * 512 + d4) = s;
}

__global__ __launch_bounds__(512) void finalize_mean_k(const float* __restrict__ part,
                                                       float* __restrict__ om) {
  int b = blockIdx.x, d = threadIdx.x;
  float s = 0.f;
  for (int c = 0; c < 32; ++c) s += part[((size_t)b * 32 + c) * 512 + d];
  om[(size_t)b * 512 + d] = s * (1.f / 1024.f);
}

// ---- generic f32 GEMM (expand only) ---------------------------------------
__global__ __launch_bounds__(256) void gemm_f32_k(
    const float* __restrict__ A, int lda,
    const float* __restrict__ W, int ldw,
    const float* __restrict__ bias,
    float* __restrict__ C, int ldc, int K) {
  __shared__ float As[16][65];
  __shared__ float Ws[16][64];
  int tid = threadIdx.x;
  int tx = tid & 15, ty = tid >> 4;
  int row0 = blockIdx.y * 64, col0 = blockIdx.x * 64;
  float acc[4][4] = {};
  int ar = tid >> 2, ac = (tid & 3) << 2;
  int wr = tid >> 4, wc = (tid & 15) << 2;
  for (int k0 = 0; k0 < K; k0 += 16) {
    float4 av = *(const float4*)(A + (size_t)(row0 + ar) * lda + k0 + ac);
    As[ac + 0][ar] = av.x; As[ac + 1][ar] = av.y;
    As[ac + 2][ar] = av.z; As[ac + 3][ar] = av.w;
    float4 wv = *(const float4*)(W + (size_t)(k0 + wr) * ldw + col0 + wc);
    *(float4*)&Ws[wr][wc] = wv;
    __syncthreads();
#pragma unroll
    for (int k = 0; k < 16; ++k) {
      float a0 = As[k][(ty << 2) + 0], a1 = As[k][(ty << 2) + 1];
      float a2 = As[k][(ty << 2) + 2], a3 = As[k][(ty << 2) + 3];
      float4 w = *(const float4*)&Ws[k][tx << 2];
      acc[0][0] += a0 * w.x; acc[0][1] += a0 * w.y; acc[0][2] += a0 * w.z; acc[0][3] += a0 * w.w;
      acc[1][0] += a1 * w.x; acc[1][1] += a1 * w.y; acc[1][2] += a1 * w.z; acc[1][3] += a1 * w.w;
      acc[2][0] += a2 * w.x; acc[2][1] += a2 * w.y; acc[2][2] += a2 * w.z; acc[2][3] += a2 * w.w;
      acc[3][0] += a3 * w.x; acc[3][1] += a3 * w.y; acc[3][2] += a3 * w.z; acc[3][3] += a3 * w.w;
    }
    __syncthreads();
  }
  float4 bv = *(const float4*)(bias + col0 + (tx << 2));
#pragma unroll
  for (int i = 0; i < 4; ++i) {
    float4 ov;
    ov.x = acc[i][0] + bv.x; ov.y = acc[i][1] + bv.y;
    ov.z = acc[i][2] + bv.z; ov.w = acc[i][3] + bv.w;
    *(float4*)(C + (size_t)(row0 + (ty << 2) + i) * ldc + col0 + (tx << 2)) = ov;
  }
}

// ---- dual-weight f32 GEMM: A[256][512] rows 0-127 -> W0, 128-255 -> W1 -----
__global__ __launch_bounds__(256) void gemm_f32_2w_k(
    const float* __restrict__ A,
    const float* __restrict__ W0, const float* __restrict__ W1,
    const float* __restrict__ b0, const float* __restrict__ b1,
    float* __restrict__ C) {
  const float* W = (blockIdx.y >= 2) ? W1 : W0;
  const float* bias = (blockIdx.y >= 2) ? b1 : b0;
  __shared__ float As[16][65];
  __shared__ float Ws[16][64];
  int tid = threadIdx.x;
  int tx = tid & 15, ty = tid >> 4;
  int row0 = blockIdx.y * 64, col0 = blockIdx.x * 64;
  float acc[4][4] = {};
  int ar = tid >> 2, ac = (tid & 3) << 2;
  int wr = tid >> 4, wc = (tid & 15) << 2;
  for (int k0 = 0; k0 < 512; k0 += 16) {
    float4 av = *(const float4*)(A + (size_t)(row0 + ar) * 512 + k0 + ac);
    As[ac + 0][ar] = av.x; As[ac + 1][ar] = av.y;
    As[ac + 2][ar] = av.z; As[ac + 3][ar] = av.w;
    float4 wv = *(const float4*)(W + (size_t)(k0 + wr) * 512 + col0 + wc);
    *(float4*)&Ws[wr][wc] = wv;
    __syncthreads();
#pragma unroll
    for (int k = 0; k < 16; ++k) {
      float a0 = As[k][(ty << 2) + 0], a1 = As[k][(ty << 2) + 1];
      float a2 = As[k][(ty << 2) + 2], a3 = As[k][(ty << 2) + 3];
      float4 w = *(const float4*)&Ws[k][tx << 2];
      acc[0][0] += a0 * w.x; acc[0][1] += a0 * w.y; acc[0][2] += a0 * w.z; acc[0][3] += a0 * w.w;
      acc[1][0] += a1 * w.x; acc[1][1] += a1 * w.y; acc[1][2] += a1 * w.z; acc[1][3] += a1 * w.w;
      acc[2][0] += a2 * w.x; acc[2][1] += a2 * w.y; acc[2][2] += a2 * w.z; acc[2][3] += a2 * w.w;
      acc[3][0] += a3 * w.x; acc[3][1] += a3 * w.y; acc[3][2] += a3 * w.z; acc[3][3] += a3 * w.w;
    }
    __syncthreads();
  }
  float4 bv = *(const float4*)(bias + col0 + (tx << 2));
#pragma unroll
  for (int i = 0; i < 4; ++i) {
    float4 ov;
    ov.x = acc[i][0] + bv.x; ov.y = acc[i][1] + bv.y;
    ov.z = acc[i][2] + bv.z; ov.w = acc[i][3] + bv.w;
    *(float4*)(C + (size_t)(row0 + (ty << 2) + i) * 512 + col0 + (tx << 2)) = ov;
  }
}

// ---- casts -----------------------------------------------------------------
__device__ __forceinline__ unsigned short f2bf(float f) {
  __hip_bfloat16 h = __float2bfloat16(f);
  return __builtin_bit_cast(unsigned short, h);
}

__global__ __launch_bounds__(256) void cast_k(const float* __restrict__ x,
                                              unsigned short* __restrict__ y, int n) {
  int i = (blockIdx.x * 256 + threadIdx.x) * 4;
  int stride = gridDim.x * 1024;
  for (; i < n; i += stride) {
    float4 v = *(const float4*)(x + i);
    ushort4 u;
    u.x = f2bf(v.x); u.y = f2bf(v.y); u.z = f2bf(v.z); u.w = f2bf(v.w);
    *(ushort4*)(y + i) = u;
  }
}

// three W[K][512] f32 -> Wt[512][K] bf16, z selects
struct W3 { const float* w[3]; unsigned short* wt[3]; };
__global__ void castT3_k(W3 a, int K) {
  const float* W = a.w[blockIdx.z];
  unsigned short* Wt = a.wt[blockIdx.z];
  __shared__ float t[32][33];
  int n0 = blockIdx.x * 32, k0 = blockIdx.y * 32;
  int tx = threadIdx.x, ty = threadIdx.y;  // (32, 8)
#pragma unroll
  for (int i = 0; i < 4; ++i)
    t[ty + 8 * i][tx] = W[(size_t)(k0 + ty + 8 * i) * 512 + n0 + tx];
  __syncthreads();
#pragma unroll
  for (int i = 0; i < 4; ++i)
    Wt[(size_t)(n0 + ty + 8 * i) * K + k0 + tx] = f2bf(t[tx][ty + 8 * i]);
}

// ---- bf16 MFMA GEMM: q,k -> bf16 out; v -> f32 out. XCD-affine decode ------
struct QkvArgs {
  const unsigned short* Wt[3];
  const float* bias[3];
  void* out[3];   // [0],[1]: bf16; [2]: f32
};

__device__ __forceinline__ void stage16(const void* g, void* l) {
  __builtin_amdgcn_global_load_lds((const __attribute__((address_space(1))) void*)g,
                                   (__attribute__((address_space(3))) void*)l, 16, 0, 0);
}

__global__ __launch_bounds__(256) void gemm_bf16_qkv(
    const unsigned short* __restrict__ A,  // bf16 [8192][K]
    QkvArgs args, int K) {
  __shared__ unsigned short As[128 * 32];
  __shared__ unsigned short Bs[128 * 32];
  // XCD-affine decode: same row-panel (y) blocks land on one XCD's L2.
  int id = blockIdx.x;
  int by = id & 63, bx = (id >> 6) & 3, bz = id >> 8;
  const unsigned short* Bt = args.Wt[bz];
  const float* bias = args.bias[bz];

  int tid = threadIdx.x;
  int l = tid & 63, w = tid >> 6;
  int row0 = by * 128, col0 = bx * 128;
  int wrow = (w & 1) * 64, wcol = (w >> 1) * 64;
  int kg = l >> 4, lr = l & 15;

  f32x4 acc[4][4] = {};

  for (int k0 = 0; k0 < K; k0 += 32) {
#pragma unroll
    for (int i = 0; i < 2; ++i) {
      int c = w * 128 + i * 64 + l;
      int r = c >> 2, s = (c & 3) * 8;
      stage16(A + (size_t)(row0 + r) * K + k0 + s, (char*)As + (size_t)(w * 128 + i * 64) * 16);
      stage16(Bt + (size_t)(col0 + r) * K + k0 + s, (char*)Bs + (size_t)(w * 128 + i * 64) * 16);
    }
    __syncthreads();
    bf16x8 af[4], bfr[4];
#pragma unroll
    for (int m = 0; m < 4; ++m) {
      af[m]  = *(const bf16x8*)(As + (size_t)(wrow + m * 16 + lr) * 32 + kg * 8);
      bfr[m] = *(const bf16x8*)(Bs + (size_t)(wcol + m * 16 + lr) * 32 + kg * 8);
    }
#pragma unroll
    for (int m = 0; m < 4; ++m)
#pragma unroll
      for (int n = 0; n < 4; ++n)
        acc[m][n] = __builtin_amdgcn_mfma_f32_16x16x32_bf16(af[m], bfr[n], acc[m][n], 0, 0, 0);
    __syncthreads();
  }

  int orow = row0 + wrow + kg * 4;
  int ocol = col0 + wcol + lr;
  float bv[4];
#pragma unroll
  for (int n = 0; n < 4; ++n) bv[n] = bias[ocol + n * 16];
  if (bz < 2) {
    unsigned short* C = (unsigned short*)args.out[bz];
#pragma unroll
    for (int m = 0; m < 4; ++m)
#pragma unroll
      for (int n = 0; n < 4; ++n)
#pragma unroll
        for (int j = 0; j < 4; ++j)
          C[(size_t)(orow + m * 16 + j) * 512 + ocol + n * 16] = f2bf(acc[m][n][j] + bv[n]);
  } else {
    float* C = (float*)args.out[2];
#pragma unroll
    for (int m = 0; m < 4; ++m)
#pragma unroll
      for (int n = 0; n < 4; ++n)
#pragma unroll
        for (int j = 0; j < 4; ++j)
          C[(size_t)(orow + m * 16 + j) * 512 + ocol + n * 16] = acc[m][n][j] + bv[n];
  }
}

// ---- attention pool: MFMA QK^T (swapped), softmax in regs, w = colsum_t(P)/64,
//      pooled = w @ V  (mean over t commuted past PV) ------------------------
__global__ __launch_bounds__(256) void attn_pool_mfma_k(
    const unsigned short* __restrict__ qbf,
    const unsigned short* __restrict__ kbf,
    const float* __restrict__ vf,
    float* __restrict__ pooled) {
  __shared__ float wlds[4][64];
  __shared__ float wf[64];
  int h = blockIdx.x, b = blockIdx.y, m = blockIdx.z;
  size_t base = ((size_t)m * 8192 + (size_t)b * 64) * 512 + h * 128;
  int tid = threadIdx.x;
  int w = tid >> 6, l = tid & 63, lr = l & 15, g = l >> 4;

  // b-frag (Q): wave w owns t' = 16w + lr; lane holds q[t'][d=32ks+8g+j]
  bf16x8 qf[4];
#pragma unroll
  for (int ks = 0; ks < 4; ++ks)
    qf[ks] = *(const bf16x8*)(qbf + base + (size_t)(16 * w + lr) * 512 + 32 * ks + 8 * g);

  // T = K·Q^T: acc[tr][j] = T[s = 16tr + 4g + j][t' = 16w + lr]
  f32x4 accT[4];
#pragma unroll
  for (int tr = 0; tr < 4; ++tr) {
    f32x4 a = {0.f, 0.f, 0.f, 0.f};
#pragma unroll
    for (int ks = 0; ks < 4; ++ks) {
      bf16x8 kfr = *(const bf16x8*)(kbf + base + (size_t)(16 * tr + lr) * 512 + 32 * ks + 8 * g);
      a = __builtin_amdgcn_mfma_f32_16x16x32_bf16(kfr, qf[ks], a, 0, 0, 0);
    }
    accT[tr] = a;
  }

  const float scale = 0.08838834764831845f;  // 1/sqrt(128)
  float p[4][4];
  float lm = -INFINITY;
#pragma unroll
  for (int tr = 0; tr < 4; ++tr)
#pragma unroll
    for (int j = 0; j < 4; ++j) { p[tr][j] = accT[tr][j] * scale; lm = fmaxf(lm, p[tr][j]); }
  lm = fmaxf(lm, __shfl_xor(lm, 16));     // combine g-groups: full max over s
  lm = fmaxf(lm, __shfl_xor(lm, 32));
  float ls = 0.f;
#pragma unroll
  for (int tr = 0; tr < 4; ++tr)
#pragma unroll
    for (int j = 0; j < 4; ++j) { p[tr][j] = expf(p[tr][j] - lm); ls += p[tr][j]; }
  ls += __shfl_xor(ls, 16);
  ls += __shfl_xor(ls, 32);
  float inv = 1.f / ls;
  // colsum over t' within wave (lanes sharing g): xor 1,2,4,8
#pragma unroll
  for (int tr = 0; tr < 4; ++tr)
#pragma unroll
    for (int j = 0; j < 4; ++j) {
      float c = p[tr][j] * inv;
      c += __shfl_xor(c, 1);
      c += __shfl_xor(c, 2);
      c += __shfl_xor(c, 4);
      c += __shfl_xor(c, 8);
      p[tr][j] = c;
    }
  if (lr == 0) {
#pragma unroll
    for (int tr = 0; tr < 4; ++tr)
#pragma unroll
      for (int j = 0; j < 4; ++j)
        wlds[w][16 * tr + 4 * g + j] = p[tr][j];
  }
  __syncthreads();
  if (tid < 64)
    wf[tid] = (wlds[0][tid] + wlds[1][tid] + wlds[2][tid] + wlds[3][tid]) * (1.f / 64.f);
  __syncthreads();

  int dd = tid & 127, t2 = tid >> 7;
  float ps = 0.f;
  for (int s = t2 * 32; s < t2 * 32 + 32; ++s)
    ps += wf[s] * vf[base + (size_t)s * 512 + dd];
  // two f32 contributions per address: commutative -> deterministic
  atomicAdd(&pooled[((size_t)m * 128 + b) * 512 + h * 128 + dd], ps);
}

// ---- row L2 normalize ------------------------------------------------------
__global__ __launch_bounds__(256) void l2norm_k(float* __restrict__ x, int C) {
  int b = blockIdx.x;
  float* row = x + (size_t)b * C;
  int tid = threadIdx.x;
  float ss = 0.f;
  for (int c = tid; c < C; c += 256) { float v = row[c]; ss += v * v; }
#pragma unroll
  for (int off = 32; off >= 1; off >>= 1) ss += __shfl_down(ss, off);
  __shared__ float wsum[4];
  if ((tid & 63) == 0) wsum[tid >> 6] = ss;
  __syncthreads();
  float total = wsum[0] + wsum[1] + wsum[2] + wsum[3];
  float inv = 1.f / fmaxf(sqrtf(total), 1e-12f);
  for (int c = tid; c < C; c += 256) row[c] *= inv;
}

// ---- G = oo[128,1024] @ feat^T ; feat col c lives in feat2[(c>>9)*128+row][c&511]
__global__ __launch_bounds__(256) void gemm_nt_k(const float* __restrict__ A,
                                                 const float* __restrict__ Bsplit,
                                                 float* __restrict__ G) {
  __shared__ float As[16][68];
  __shared__ float Bs[16][68];
  int tid = threadIdx.x, tx = tid & 15, ty = tid >> 4;
  int row0 = blockIdx.y * 64, col0 = blockIdx.x * 64;
  float acc[4][4] = {};
  int ar = tid >> 2, ac = (tid & 3) << 2;
  for (int k0 = 0; k0 < 1024; k0 += 16) {
    float4 av = *(const float4*)(A + (size_t)(row0 + ar) * 1024 + k0 + ac);
    As[ac + 0][ar] = av.x; As[ac + 1][ar] = av.y;
    As[ac + 2][ar] = av.z; As[ac + 3][ar] = av.w;
    float4 bv = *(const float4*)(Bsplit + (size_t)((k0 >> 9) * 128 + col0 + ar) * 512 + (k0 & 511) + ac);
    Bs[ac + 0][ar] = bv.x; Bs[ac + 1][ar] = bv.y;
    Bs[ac + 2][ar] = bv.z; Bs[ac + 3][ar] = bv.w;
    __syncthreads();
#pragma unroll
    for (int k = 0; k < 16; ++k) {
      float4 a4 = *(const float4*)&As[k][ty << 2];
      float4 b4 = *(const float4*)&Bs[k][tx << 2];
      acc[0][0] += a4.x * b4.x; acc[0][1] += a4.x * b4.y; acc[0][2] += a4.x * b4.z; acc[0][3] += a4.x * b4.w;
      acc[1][0] += a4.y * b4.x; acc[1][1] += a4.y * b4.y; acc[1][2] += a4.y * b4.z; acc[1][3] += a4.y * b4.w;
      acc[2][0] += a4.z * b4.x; acc[2][1] += a4.z * b4.y; acc[2][2] += a4.z * b4.z; acc[2][3] += a4.z * b4.w;
      acc[3][0] += a4.w * b4.x; acc[3][1] += a4.w * b4.y; acc[3][2] += a4.w * b4.z; acc[3][3] += a4.w * b4.w;
    }
    __syncthreads();
  }
#pragma unroll
  for (int i = 0; i < 4; ++i)
    *(float4*)(G + (size_t)(row0 + (ty << 2) + i) * 128 + col0 + (tx << 2)) = *(float4*)acc[i];
}

// ---- final loss/acc (reads G with circulant remap) -------------------------
__global__ __launch_bounds__(128) void final_k(const float* __restrict__ G,
                                               const int* __restrict__ gmask,
                                               float* __restrict__ out) {
  __shared__ float cm[2][128], vd[2][128], tp[2][128], cv[2][128];
  __shared__ int gm[128];
  int b = threadIdx.x;
  gm[b] = gmask[b];
  __syncthreads();
  for (int r = 0; r < 2; ++r) {
    bool gb = gm[b] != 0;
    float s0 = G[b * 128 + b];  // i=0 -> j=b, both orientations
    int cnt = 0;
    float lsum = 0.f, selsum = 0.f, smax = -INFINITY;
    bool anym = false;
    for (int i = 0; i < 128; ++i) {
      int j = (b - i + 128) & 127;
      bool mk = gb && (gm[j] != 0);
      float sv = (r == 0) ? G[b * 128 + j] : G[j * 128 + b];
      if (mk) {
        selsum += sv; anym = true;
        smax = fmaxf(smax, sv);
        if (i >= 1) { cnt++; lsum += fmaxf(0.f, 1.f + sv - s0); }
      }
    }
    cm[r][b] = (cnt > 0) ? (lsum / (float)cnt) : 0.f;
    vd[r][b] = (cnt > 0) ? 1.f : 0.f;
    bool colvalid = (selsum != 0.f) && anym;
    tp[r][b] = (colvalid && (s0 >= smax)) ? 1.f : 0.f;
    cv[r][b] = colvalid ? 1.f : 0.f;
  }
  __syncthreads();
  if (b == 0) {
    float loss = 0.f, acc = 0.f;
    for (int r = 0; r < 2; ++r) {
      float scm = 0, svd = 0, stp = 0, scv = 0;
      for (int i = 0; i < 128; ++i) { scm += cm[r][i]; svd += vd[r][i]; stp += tp[r][i]; scv += cv[r][i]; }
      loss += scm / fmaxf(svd, 1.f);
      acc += stp / fmaxf(scv, 1.f);
    }
    out[0] = loss;
    out[1] = acc * 0.5f;
  }
}

extern "C" void kernel_launch(void* const* d_in, const int* in_sizes, int n_in,
                              void* d_out, int out_size, void* d_ws, size_t ws_size,
                              hipStream_t stream) {
  const float* o     = (const float*)d_in[0];
  const float* rgb   = (const float*)d_in[1];
  const float* audio = (const float*)d_in[2];
  const int* gmask   = (const int*)d_in[3];
  const float* W[2][10];
  for (int m = 0; m < 2; ++m)
    for (int w = 0; w < 10; ++w) W[m][w] = (const float*)d_in[4 + m * 10 + w];
  const float* expand_W = (const float*)d_in[24];
  const float* expand_b = (const float*)d_in[25];

  char* ws = (char*)d_ws;
  float* part = (float*)(ws + B_PART);
  float* om   = (float*)(ws + B_OM);
  float* oo   = (float*)(ws + B_OO);
  float* G    = (float*)(ws + B_G);
  float* pp2  = (float*)(ws + B_PP);
  float* po2  = (float*)(ws + B_PO);
  float* feat2= (float*)(ws + B_FEAT);
  unsigned short* qbf = (unsigned short*)(ws + B_QBF);
  unsigned short* kbf = (unsigned short*)(ws + B_KBF);
  float* vf   = (float*)(ws + B_VF);
  unsigned short* xbf = (unsigned short*)(ws + B_XBF);
  unsigned short* wt0 = (unsigned short*)(ws + B_WT);
  unsigned short* wt1 = wt0 + (size_t)512 * 2048;
  unsigned short* wt2 = wt1 + (size_t)512 * 2048;

  // oo branch (f32)
  mean_partial_k<<<dim3(16, 128), 256, 0, stream>>>(o, part);
  finalize_mean_k<<<128, 512, 0, stream>>>(part, om);
  gemm_f32_k<<<dim3(16, 2), 256, 0, stream>>>(om, 512, expand_W, 1024, expand_b, oo, 1024, 512);
  l2norm_k<<<128, 256, 0, stream>>>(oo, 1024);

  // modality branches: cast + qkv (q,k bf16; v f32)
  const float* Xs[2] = {rgb, audio};
  const int Ks[2] = {2048, 128};
  for (int m = 0; m < 2; ++m) {
    int K = Ks[m];
    cast_k<<<dim3(m == 0 ? 2048 : 512), 256, 0, stream>>>(Xs[m], xbf, 8192 * K);
    W3 w3;
    w3.w[0] = W[m][0]; w3.w[1] = W[m][2]; w3.w[2] = W[m][4];
    w3.wt[0] = wt0; w3.wt[1] = wt1; w3.wt[2] = wt2;
    castT3_k<<<dim3(16, K / 32, 3), dim3(32, 8), 0, stream>>>(w3, K);
    QkvArgs args;
    args.Wt[0] = wt0; args.Wt[1] = wt1; args.Wt[2] = wt2;
    args.bias[0] = W[m][1]; args.bias[1] = W[m][3]; args.bias[2] = W[m][5];
    args.out[0] = qbf + (size_t)m * 8192 * 512;
    args.out[1] = kbf + (size_t)m * 8192 * 512;
    args.out[2] = vf + (size_t)m * 8192 * 512;
    gemm_bf16_qkv<<<768, 256, 0, stream>>>(xbf, args, K);
  }

  // attention pools (both modalities)
  hipMemsetAsync(pp2, 0, 2 * 128 * 512 * sizeof(float), stream);
  attn_pool_mfma_k<<<dim3(4, 128, 2), 256, 0, stream>>>(qbf, kbf, vf, pp2);

  // po = pp @ Wo + bo ; feat = po @ W2 + b2   (batched over modalities)
  gemm_f32_2w_k<<<dim3(8, 4), 256, 0, stream>>>(pp2, W[0][6], W[1][6], W[0][7], W[1][7], po2);
  gemm_f32_2w_k<<<dim3(8, 4), 256, 0, stream>>>(po2, W[0][8], W[1][8], W[0][9], W[1][9], feat2);

  // ranking: G = oo @ feat^T, then remapped loss/acc
  gemm_nt_k<<<dim3(2, 2), 256, 0, stream>>>(oo, feat2, G);
  final_k<<<1, 128, 0, stream>>>(G, gmask, (float*)d_out);
}